// Round 1
// baseline (123.566 us; speedup 1.0000x reference)
//
#include <hip/hip_runtime.h>

#define HW 16384
#define NB 7
#define NS 7
#define NN 32   // b*f

__global__ void zero_out_kernel(float* out) {
    if (threadIdx.x == 0 && blockIdx.x == 0) out[0] = 0.0f;
}

// One block: 256 threads, 4 pixels/thread -> 1024 pixels. grid = (16, 32).
__global__ __launch_bounds__(256) void em_loss_kernel(
    const float* __restrict__ seg,    // [N, NB, HW]
    const float* __restrict__ masks,  // [N, NS, HW]
    const float* __restrict__ rec,    // [N, NB, 3, HW]
    const float* __restrict__ tgt,    // [N, 3, HW]
    const float* __restrict__ mvis,   // [N, NS, HW]
    const float* __restrict__ ai,     // [N, NS, NB]
    float* __restrict__ out)
{
    const int n   = blockIdx.y;
    const int tid = threadIdx.x;
    const int pix = (blockIdx.x * blockDim.x + tid) * 4;

    __shared__ float s_ai[NS * NB];
    __shared__ float s_A[NB];
    __shared__ float s_part[4];

    if (tid < NS * NB) s_ai[tid] = ai[n * NS * NB + tid];
    __syncthreads();
    if (tid < NB) {
        float a = 0.0f;
        #pragma unroll
        for (int s = 0; s < NS; ++s) a += s_ai[s * NB + tid];
        s_A[tid] = a;
    }
    __syncthreads();

    const float* seg_n = seg   + (size_t)n * NB * HW + pix;
    const float* rec_n = rec   + (size_t)n * NB * 3 * HW + pix;
    const float* tgt_n = tgt   + (size_t)n * 3 * HW + pix;
    const float* msk_n = masks + (size_t)n * NS * HW + pix;
    const float* mv_n  = mvis  + (size_t)n * NS * HW + pix;

    // --- target pixels (3 channels x 4 pixels) ---
    float t[3][4];
    #pragma unroll
    for (int c = 0; c < 3; ++c) {
        float4 v = *reinterpret_cast<const float4*>(tgt_n + c * HW);
        t[c][0] = v.x; t[c][1] = v.y; t[c][2] = v.z; t[c][3] = v.w;
    }

    // --- d2[b] = sum_c (rec - tgt)^2, per pixel component ---
    float d2[NB][4];
    #pragma unroll
    for (int b = 0; b < NB; ++b) {
        #pragma unroll
        for (int j = 0; j < 4; ++j) d2[b][j] = 0.0f;
        #pragma unroll
        for (int c = 0; c < 3; ++c) {
            float4 v = *reinterpret_cast<const float4*>(rec_n + (b * 3 + c) * HW);
            float r[4] = {v.x, v.y, v.z, v.w};
            #pragma unroll
            for (int j = 0; j < 4; ++j) {
                float d = r[j] - t[c][j];
                d2[b][j] += d * d;
            }
        }
    }

    // --- BCE pieces: base = sum_b A[b]*L0[b]; Ldiff[b] = L1[b]-L0[b] ---
    float base[4] = {0.f, 0.f, 0.f, 0.f};
    float Ldiff[NB][4];
    #pragma unroll
    for (int b = 0; b < NB; ++b) {
        float4 v = *reinterpret_cast<const float4*>(seg_n + b * HW);
        float sv[4] = {v.x, v.y, v.z, v.w};
        float A = s_A[b];
        #pragma unroll
        for (int j = 0; j < 4; ++j) {
            // clip(log(p), -100) negated => min(-log(p), 100)
            float L1 = fminf(-__logf(sv[j]), 100.0f);
            float L0 = fminf(-__logf(1.0f - sv[j]), 100.0f);
            base[j] += A * L0;
            Ldiff[b][j] = L1 - L0;
        }
    }

    // --- accumulate over slots s ---
    float bce[4] = {base[0], base[1], base[2], base[3]};
    float mse[4] = {0.f, 0.f, 0.f, 0.f};
    #pragma unroll
    for (int s = 0; s < NS; ++s) {
        float dotL[4] = {0.f, 0.f, 0.f, 0.f};
        float dotD[4] = {0.f, 0.f, 0.f, 0.f};
        #pragma unroll
        for (int b = 0; b < NB; ++b) {
            float a = s_ai[s * NB + b];
            #pragma unroll
            for (int j = 0; j < 4; ++j) {
                dotL[j] += a * Ldiff[b][j];
                dotD[j] += a * d2[b][j];
            }
        }
        float4 mk = *reinterpret_cast<const float4*>(msk_n + s * HW);
        float4 mv = *reinterpret_cast<const float4*>(mv_n + s * HW);
        float mkv[4] = {mk.x, mk.y, mk.z, mk.w};
        float mvv[4] = {mv.x, mv.y, mv.z, mv.w};
        #pragma unroll
        for (int j = 0; j < 4; ++j) {
            bce[j] += (mkv[j] > 0.5f) ? dotL[j] : 0.0f;
            mse[j] += (mvv[j] > 0.5f) ? dotD[j] : 0.0f;
        }
    }

    const float inv_hw = 1.0f / (float)HW;
    float acc = 0.0f;
    #pragma unroll
    for (int j = 0; j < 4; ++j) acc += bce[j] * inv_hw + 0.1f * mse[j];

    // --- wave-64 reduction ---
    #pragma unroll
    for (int off = 32; off > 0; off >>= 1) acc += __shfl_down(acc, off, 64);

    const int wave = tid >> 6;
    const int lane = tid & 63;
    if (lane == 0) s_part[wave] = acc;
    __syncthreads();
    if (tid == 0) {
        float tsum = s_part[0] + s_part[1] + s_part[2] + s_part[3];
        atomicAdd(out, tsum * (20.0f / 1568.0f));  // LOSS_WEIGHT / (b*f*ns*nb)
    }
}

extern "C" void kernel_launch(void* const* d_in, const int* in_sizes, int n_in,
                              void* d_out, int out_size, void* d_ws, size_t ws_size,
                              hipStream_t stream) {
    const float* seg  = (const float*)d_in[0];
    const float* msk  = (const float*)d_in[1];
    const float* rec  = (const float*)d_in[2];
    const float* tgt  = (const float*)d_in[3];
    const float* mvis = (const float*)d_in[4];
    const float* ai   = (const float*)d_in[5];
    float* out = (float*)d_out;

    zero_out_kernel<<<1, 64, 0, stream>>>(out);
    dim3 grid(HW / (256 * 4), NN);  // (16, 32) = 512 blocks
    em_loss_kernel<<<grid, 256, 0, stream>>>(seg, msk, rec, tgt, mvis, ai, out);
}

// Round 2
// 115.799 us; speedup vs baseline: 1.0671x; 1.0671x over previous
//
#include <hip/hip_runtime.h>

#define HW 16384
#define NB 7
#define NS 7
#define NN 32   // b*f
#define BLK 256
#define GRIDX (HW / BLK)          // 64
#define NPART (GRIDX * NN)        // 2048 partials

// One thread = one pixel. grid = (64, 32) = 2048 blocks, 8192 waves.
__global__ __launch_bounds__(BLK, 4) void em_loss_main(
    const float* __restrict__ seg,    // [N, NB, HW]
    const float* __restrict__ masks,  // [N, NS, HW]
    const float* __restrict__ rec,    // [N, NB, 3, HW]
    const float* __restrict__ tgt,    // [N, 3, HW]
    const float* __restrict__ mvis,   // [N, NS, HW]
    const float* __restrict__ ai,     // [N, NS, NB]
    float* __restrict__ partial)      // [NPART]
{
    const int n   = blockIdx.y;
    const int tid = threadIdx.x;
    const int pix = blockIdx.x * BLK + tid;

    __shared__ float s_ai[NS * NB];
    __shared__ float s_A[NB];
    __shared__ float s_part[4];

    if (tid < NS * NB) s_ai[tid] = ai[n * NS * NB + tid];
    __syncthreads();
    if (tid < NB) {
        float a = 0.0f;
        #pragma unroll
        for (int s = 0; s < NS; ++s) a += s_ai[s * NB + tid];
        s_A[tid] = a;
    }
    __syncthreads();

    const float* seg_n = seg   + (size_t)n * NB * HW + pix;
    const float* rec_n = rec   + (size_t)n * NB * 3 * HW + pix;
    const float* tgt_n = tgt   + (size_t)n * 3 * HW + pix;
    const float* msk_n = masks + (size_t)n * NS * HW + pix;
    const float* mv_n  = mvis  + (size_t)n * NS * HW + pix;

    // --- load all 14 mask values (independent scalar loads, deep MLP) ---
    float mkv[NS], mvv[NS];
    #pragma unroll
    for (int s = 0; s < NS; ++s) mkv[s] = msk_n[s * HW];
    #pragma unroll
    for (int s = 0; s < NS; ++s) mvv[s] = mv_n[s * HW];

    // --- per-buffer effective weights: W_L[b] = sum_s m_s*ai, W_D[b] = sum_s mv_s*ai ---
    float wl[NB], wd[NB];
    #pragma unroll
    for (int b = 0; b < NB; ++b) { wl[b] = 0.0f; wd[b] = 0.0f; }
    #pragma unroll
    for (int s = 0; s < NS; ++s) {
        const float bm = (mkv[s] > 0.5f) ? 1.0f : 0.0f;
        const float bv = (mvv[s] > 0.5f) ? 1.0f : 0.0f;
        #pragma unroll
        for (int b = 0; b < NB; ++b) {
            const float a = s_ai[s * NB + b];
            wl[b] += bm * a;
            wd[b] += bv * a;
        }
    }

    // --- targets (3 scalars) ---
    const float t0 = tgt_n[0];
    const float t1 = tgt_n[HW];
    const float t2 = tgt_n[2 * HW];

    // --- single pass over buffers: seg + 3 rec channels each ---
    float acc_bce = 0.0f, acc_mse = 0.0f;
    #pragma unroll
    for (int b = 0; b < NB; ++b) {
        const float sv = seg_n[b * HW];
        const float r0 = rec_n[(b * 3 + 0) * HW];
        const float r1 = rec_n[(b * 3 + 1) * HW];
        const float r2 = rec_n[(b * 3 + 2) * HW];
        const float L1 = fminf(-__logf(sv), 100.0f);
        const float L0 = fminf(-__logf(1.0f - sv), 100.0f);
        acc_bce += s_A[b] * L0 + wl[b] * (L1 - L0);
        const float d0 = r0 - t0, d1 = r1 - t1, d2 = r2 - t2;
        acc_mse += wd[b] * (d0 * d0 + d1 * d1 + d2 * d2);
    }

    float acc = acc_bce * (1.0f / (float)HW) + 0.1f * acc_mse;

    // --- wave-64 + block reduction ---
    #pragma unroll
    for (int off = 32; off > 0; off >>= 1) acc += __shfl_down(acc, off, 64);
    const int wave = tid >> 6;
    const int lane = tid & 63;
    if (lane == 0) s_part[wave] = acc;
    __syncthreads();
    if (tid == 0) {
        partial[blockIdx.y * GRIDX + blockIdx.x] =
            s_part[0] + s_part[1] + s_part[2] + s_part[3];
    }
}

__global__ __launch_bounds__(BLK) void em_loss_reduce(
    const float* __restrict__ partial, float* __restrict__ out)
{
    __shared__ float s_part[4];
    const int tid = threadIdx.x;
    float a = 0.0f;
    #pragma unroll
    for (int i = 0; i < NPART / BLK; ++i) a += partial[i * BLK + tid];
    #pragma unroll
    for (int off = 32; off > 0; off >>= 1) a += __shfl_down(a, off, 64);
    const int wave = tid >> 6;
    const int lane = tid & 63;
    if (lane == 0) s_part[wave] = a;
    __syncthreads();
    if (tid == 0)
        out[0] = (s_part[0] + s_part[1] + s_part[2] + s_part[3]) * (20.0f / 1568.0f);
}

extern "C" void kernel_launch(void* const* d_in, const int* in_sizes, int n_in,
                              void* d_out, int out_size, void* d_ws, size_t ws_size,
                              hipStream_t stream) {
    const float* seg  = (const float*)d_in[0];
    const float* msk  = (const float*)d_in[1];
    const float* rec  = (const float*)d_in[2];
    const float* tgt  = (const float*)d_in[3];
    const float* mvis = (const float*)d_in[4];
    const float* ai   = (const float*)d_in[5];
    float* out     = (float*)d_out;
    float* partial = (float*)d_ws;   // 2048 floats, overwritten every launch

    dim3 grid(GRIDX, NN);
    em_loss_main<<<grid, BLK, 0, stream>>>(seg, msk, rec, tgt, mvis, ai, partial);
    em_loss_reduce<<<1, BLK, 0, stream>>>(partial, out);
}

// Round 3
// 115.373 us; speedup vs baseline: 1.0710x; 1.0037x over previous
//
#include <hip/hip_runtime.h>

#define HW 16384
#define NB 7
#define NS 7
#define NN 32   // b*f
#define BLK 256
#define PPT 2                        // pixels per thread (float2 loads)
#define GRIDX (HW / (BLK * PPT))     // 32
#define NPART (GRIDX * NN)           // 1024 partials

// Two pixels per thread via float2. grid = (32, 32) = 1024 blocks, 4096 waves.
__global__ __launch_bounds__(BLK, 4) void em_loss_main(
    const float* __restrict__ seg,    // [N, NB, HW]
    const float* __restrict__ masks,  // [N, NS, HW]
    const float* __restrict__ rec,    // [N, NB, 3, HW]
    const float* __restrict__ tgt,    // [N, 3, HW]
    const float* __restrict__ mvis,   // [N, NS, HW]
    const float* __restrict__ ai,     // [N, NS, NB]
    float* __restrict__ partial)      // [NPART]
{
    const int n   = blockIdx.y;
    const int tid = threadIdx.x;
    const int pix = (blockIdx.x * BLK + tid) * PPT;

    __shared__ float s_ai[NS * NB];
    __shared__ float s_A[NB];
    __shared__ float s_part[4];

    if (tid < NS * NB) s_ai[tid] = ai[n * NS * NB + tid];
    __syncthreads();
    if (tid < NB) {
        float a = 0.0f;
        #pragma unroll
        for (int s = 0; s < NS; ++s) a += s_ai[s * NB + tid];
        s_A[tid] = a;
    }
    __syncthreads();

    const float* seg_n = seg   + (size_t)n * NB * HW + pix;
    const float* rec_n = rec   + (size_t)n * NB * 3 * HW + pix;
    const float* tgt_n = tgt   + (size_t)n * 3 * HW + pix;
    const float* msk_n = masks + (size_t)n * NS * HW + pix;
    const float* mv_n  = mvis  + (size_t)n * NS * HW + pix;

    // --- per-buffer effective weights per pixel slot j:
    //     wl[j][b] = sum_s (mask>0.5)*ai,  wd[j][b] = sum_s (mvis>0.5)*ai ---
    float wl[PPT][NB], wd[PPT][NB];
    #pragma unroll
    for (int j = 0; j < PPT; ++j)
        #pragma unroll
        for (int b = 0; b < NB; ++b) { wl[j][b] = 0.0f; wd[j][b] = 0.0f; }

    #pragma unroll
    for (int s = 0; s < NS; ++s) {
        const float2 mk = *reinterpret_cast<const float2*>(msk_n + s * HW);
        const float2 mv = *reinterpret_cast<const float2*>(mv_n + s * HW);
        const float bm[PPT] = { (mk.x > 0.5f) ? 1.0f : 0.0f, (mk.y > 0.5f) ? 1.0f : 0.0f };
        const float bv[PPT] = { (mv.x > 0.5f) ? 1.0f : 0.0f, (mv.y > 0.5f) ? 1.0f : 0.0f };
        #pragma unroll
        for (int b = 0; b < NB; ++b) {
            const float a = s_ai[s * NB + b];
            #pragma unroll
            for (int j = 0; j < PPT; ++j) {
                wl[j][b] += bm[j] * a;
                wd[j][b] += bv[j] * a;
            }
        }
    }

    // --- targets ---
    const float2 t0 = *reinterpret_cast<const float2*>(tgt_n);
    const float2 t1 = *reinterpret_cast<const float2*>(tgt_n + HW);
    const float2 t2 = *reinterpret_cast<const float2*>(tgt_n + 2 * HW);
    const float tr0[PPT] = { t0.x, t0.y };
    const float tr1[PPT] = { t1.x, t1.y };
    const float tr2[PPT] = { t2.x, t2.y };

    // --- single pass over buffers ---
    float acc_bce = 0.0f, acc_mse = 0.0f;
    #pragma unroll
    for (int b = 0; b < NB; ++b) {
        const float2 sv = *reinterpret_cast<const float2*>(seg_n + b * HW);
        const float2 r0 = *reinterpret_cast<const float2*>(rec_n + (b * 3 + 0) * HW);
        const float2 r1 = *reinterpret_cast<const float2*>(rec_n + (b * 3 + 1) * HW);
        const float2 r2 = *reinterpret_cast<const float2*>(rec_n + (b * 3 + 2) * HW);
        const float svv[PPT] = { sv.x, sv.y };
        const float rv0[PPT] = { r0.x, r0.y };
        const float rv1[PPT] = { r1.x, r1.y };
        const float rv2[PPT] = { r2.x, r2.y };
        const float A = s_A[b];
        #pragma unroll
        for (int j = 0; j < PPT; ++j) {
            const float L1 = fminf(-__logf(svv[j]), 100.0f);
            const float L0 = fminf(-__logf(1.0f - svv[j]), 100.0f);
            acc_bce += A * L0 + wl[j][b] * (L1 - L0);
            const float d0 = rv0[j] - tr0[j];
            const float d1 = rv1[j] - tr1[j];
            const float d2 = rv2[j] - tr2[j];
            acc_mse += wd[j][b] * (d0 * d0 + d1 * d1 + d2 * d2);
        }
    }

    float acc = acc_bce * (1.0f / (float)HW) + 0.1f * acc_mse;

    // --- wave-64 + block reduction ---
    #pragma unroll
    for (int off = 32; off > 0; off >>= 1) acc += __shfl_down(acc, off, 64);
    const int wave = tid >> 6;
    const int lane = tid & 63;
    if (lane == 0) s_part[wave] = acc;
    __syncthreads();
    if (tid == 0) {
        partial[blockIdx.y * GRIDX + blockIdx.x] =
            s_part[0] + s_part[1] + s_part[2] + s_part[3];
    }
}

__global__ __launch_bounds__(BLK) void em_loss_reduce(
    const float* __restrict__ partial, float* __restrict__ out)
{
    __shared__ float s_part[4];
    const int tid = threadIdx.x;
    float a = 0.0f;
    #pragma unroll
    for (int i = 0; i < NPART / BLK; ++i) a += partial[i * BLK + tid];
    #pragma unroll
    for (int off = 32; off > 0; off >>= 1) a += __shfl_down(a, off, 64);
    const int wave = tid >> 6;
    const int lane = tid & 63;
    if (lane == 0) s_part[wave] = a;
    __syncthreads();
    if (tid == 0)
        out[0] = (s_part[0] + s_part[1] + s_part[2] + s_part[3]) * (20.0f / 1568.0f);
}

extern "C" void kernel_launch(void* const* d_in, const int* in_sizes, int n_in,
                              void* d_out, int out_size, void* d_ws, size_t ws_size,
                              hipStream_t stream) {
    const float* seg  = (const float*)d_in[0];
    const float* msk  = (const float*)d_in[1];
    const float* rec  = (const float*)d_in[2];
    const float* tgt  = (const float*)d_in[3];
    const float* mvis = (const float*)d_in[4];
    const float* ai   = (const float*)d_in[5];
    float* out     = (float*)d_out;
    float* partial = (float*)d_ws;   // 1024 floats, overwritten every launch

    dim3 grid(GRIDX, NN);
    em_loss_main<<<grid, BLK, 0, stream>>>(seg, msk, rec, tgt, mvis, ai, partial);
    em_loss_reduce<<<1, BLK, 0, stream>>>(partial, out);
}